// Round 1
// baseline (194.467 us; speedup 1.0000x reference)
//
#include <hip/hip_runtime.h>

// ---------------------------------------------------------------------------
// AuxiliaryYFixed: loc = z_ins @ W.T + b  ([N,128] -> [N]);
//                  M[b] = max over bag (sorted bag_idx), empty bags -> 0.0
// Output layout: d_out = [ M (B floats) | loc (N floats) ]
// Memory-bound: ~1.04 GB traffic -> target ~170 us at ~6.3 TB/s.
// ---------------------------------------------------------------------------

// Monotone float -> uint32 key (order-preserving). Key 0 <=> bits 0xFFFFFFFF
// (= negative NaN) which randn inputs never produce, so 0 is the "empty"
// sentinel for the per-bag atomicMax accumulator.
__device__ __forceinline__ unsigned int flip_f32(float f) {
    unsigned int u = __float_as_uint(f);
    return u ^ ((unsigned int)((int)u >> 31) | 0x80000000u);
}
__device__ __forceinline__ float unflip_f32(unsigned int u) {
    unsigned int b = (u & 0x80000000u) ? (u ^ 0x80000000u) : ~u;
    return __uint_as_float(b);
}

__global__ __launch_bounds__(256, 4) void linseg_main_kernel(
    const float* __restrict__ z,      // [N,128]
    const int*   __restrict__ bag,    // [N] (sorted, values in [0,B))
    const float* __restrict__ W,      // [128]
    const float* __restrict__ bptr,   // [1]
    float*       __restrict__ loc,    // [N]  (d_out + B)
    unsigned int* __restrict__ Mu,    // [B]  workspace keys, pre-zeroed
    int N)
{
    __shared__ float smem[4][64];     // per-wave row-result transpose buffer
    const int lane = threadIdx.x & 63;
    const int wid  = threadIdx.x >> 6;
    const int half = lane >> 5;       // which row of the pair this lane loads
    const int q    = lane & 31;       // float4 slot within the 128-wide row
    const float4 w4 = reinterpret_cast<const float4*>(W)[q];
    const float bias = bptr[0];

    const int ntiles = (N + 63) >> 6;                       // 64 rows per tile
    const int gwaves = (int)((gridDim.x * blockDim.x) >> 6);
    const int gw0    = (int)((blockIdx.x * blockDim.x + threadIdx.x) >> 6);

    for (int t = gw0; t < ntiles; t += gwaves) {
        const int base = t << 6;
        // --- 64 row dots, 2 rows per iteration (1 KiB coalesced per load) ---
        #pragma unroll 4
        for (int i = 0; i < 32; ++i) {
            const int row = base + 2 * i + half;
            float s = 0.0f;
            if (row < N) {
                const float4 v =
                    reinterpret_cast<const float4*>(z + (size_t)row * 128)[q];
                s = v.x * w4.x + v.y * w4.y + v.z * w4.z + v.w * w4.w;
            }
            // reduce across the 32-lane half (masks <32 stay within half)
            s += __shfl_xor(s, 16);
            s += __shfl_xor(s, 8);
            s += __shfl_xor(s, 4);
            s += __shfl_xor(s, 2);
            s += __shfl_xor(s, 1);
            if (q == i) smem[wid][2 * i + half] = s + bias;   // 2 lanes write
        }
        // --- transpose: lane <- row base+lane (intra-wave LDS, no barrier) ---
        const int row = base + lane;
        const float val = smem[wid][lane];
        if (row < N) loc[row] = val;                          // 256 B coalesced

        // --- segmented max over sorted bags within the 64-row window ---
        const int mybag = (row < N) ? bag[row] : -1;
        float v = val;
        #pragma unroll
        for (int s = 1; s < 64; s <<= 1) {
            const float ov = __shfl_up(v, s);
            const int   ob = __shfl_up(mybag, s);
            if (lane >= s && ob == mybag) v = fmaxf(v, ov);
        }
        const int nxt = __shfl_down(mybag, 1);
        const bool tail = (lane == 63) || (nxt != mybag);
        if (tail && mybag >= 0)
            atomicMax(&Mu[mybag], flip_f32(v));               // ~1-2 per tile
    }
}

__global__ void linseg_finalize_kernel(const unsigned int* __restrict__ Mu,
                                       float* __restrict__ M, int B)
{
    const int i = blockIdx.x * blockDim.x + threadIdx.x;
    if (i < B) {
        const unsigned int u = Mu[i];
        M[i] = (u == 0u) ? 0.0f : unflip_f32(u);
    }
}

extern "C" void kernel_launch(void* const* d_in, const int* in_sizes, int n_in,
                              void* d_out, int out_size, void* d_ws, size_t ws_size,
                              hipStream_t stream) {
    const float* z    = (const float*)d_in[0];
    const int*   bag  = (const int*)  d_in[1];
    const float* W    = (const float*)d_in[2];
    const float* bptr = (const float*)d_in[3];

    const int N = in_sizes[1];            // bag_idx element count
    const int B = out_size - N;           // M is the first output chunk

    float* M_out   = (float*)d_out;       // [B]
    float* loc_out = (float*)d_out + B;   // [N]
    unsigned int* Mu = (unsigned int*)d_ws;

    // zero the per-bag key accumulator (graph-capturable async memset)
    hipMemsetAsync(Mu, 0, (size_t)B * sizeof(unsigned int), stream);

    const int ntiles = (N + 63) >> 6;
    int blocks = (ntiles + 3) / 4;        // 4 waves per 256-thread block
    if (blocks > 2048) blocks = 2048;     // grid-stride the rest
    if (blocks < 1) blocks = 1;

    linseg_main_kernel<<<blocks, 256, 0, stream>>>(z, bag, W, bptr,
                                                   loc_out, Mu, N);
    linseg_finalize_kernel<<<(B + 255) / 256, 256, 0, stream>>>(Mu, M_out, B);
}

// Round 3
// 174.548 us; speedup vs baseline: 1.1141x; 1.1141x over previous
//
#include <hip/hip_runtime.h>

// ---------------------------------------------------------------------------
// AuxiliaryYFixed: loc = z_ins @ W.T + b  ([N,128] -> [N]);
//                  M[b] = max over bag (sorted bag_idx), empty bags -> 0.0
// Output layout: d_out = [ M (B floats) | loc (N floats) ]
// Memory-bound: ~1.04 GB traffic. R1: 194.5 us (5.35 TB/s eff).
// R3: nontemporal streaming via native ext_vector_type (HIP float4 is a
//     class, rejected by the builtin) + 4 rows/iter. Target ~180 us.
// ---------------------------------------------------------------------------

typedef float vfloat4 __attribute__((ext_vector_type(4)));

__device__ __forceinline__ unsigned int flip_f32(float f) {
    unsigned int u = __float_as_uint(f);
    return u ^ ((unsigned int)((int)u >> 31) | 0x80000000u);
}
__device__ __forceinline__ float unflip_f32(unsigned int u) {
    unsigned int b = (u & 0x80000000u) ? (u ^ 0x80000000u) : ~u;
    return __uint_as_float(b);
}

__global__ __launch_bounds__(256, 4) void linseg_main_kernel(
    const float* __restrict__ z,      // [N,128]
    const int*   __restrict__ bag,    // [N] (sorted, values in [0,B))
    const float* __restrict__ W,      // [128]
    const float* __restrict__ bptr,   // [1]
    float*       __restrict__ loc,    // [N]  (d_out + B)
    unsigned int* __restrict__ Mu,    // [B]  workspace keys, pre-zeroed
    int N)
{
    __shared__ float smem[4][64];     // per-wave row-result transpose buffer
    const int lane = threadIdx.x & 63;
    const int wid  = threadIdx.x >> 6;
    const int half = lane >> 5;       // which row of a pair this lane loads
    const int q    = lane & 31;       // float4 slot within the 128-wide row
    const vfloat4 w4 = reinterpret_cast<const vfloat4*>(W)[q];
    const float bias = bptr[0];

    const int ntiles = (N + 63) >> 6;                       // 64 rows per tile
    const int gwaves = (int)((gridDim.x * blockDim.x) >> 6);
    const int gw0    = (int)((blockIdx.x * blockDim.x + threadIdx.x) >> 6);

    for (int t = gw0; t < ntiles; t += gwaves) {
        const int base = t << 6;
        // --- 64 row dots, 4 rows per iteration as two independent pairs ---
        #pragma unroll 4
        for (int i = 0; i < 16; ++i) {
            const int rowA = base + 4 * i + half;
            const int rowB = rowA + 2;
            vfloat4 vA = (vfloat4)0.0f;
            vfloat4 vB = (vfloat4)0.0f;
            if (rowA < N)
                vA = __builtin_nontemporal_load(
                    reinterpret_cast<const vfloat4*>(z + (size_t)rowA * 128) + q);
            if (rowB < N)
                vB = __builtin_nontemporal_load(
                    reinterpret_cast<const vfloat4*>(z + (size_t)rowB * 128) + q);
            float sA = vA.x * w4.x + vA.y * w4.y + vA.z * w4.z + vA.w * w4.w;
            float sB = vB.x * w4.x + vB.y * w4.y + vB.z * w4.z + vB.w * w4.w;
            // two independent butterflies, interleaved (within 32-lane halves)
            sA += __shfl_xor(sA, 16);  sB += __shfl_xor(sB, 16);
            sA += __shfl_xor(sA, 8);   sB += __shfl_xor(sB, 8);
            sA += __shfl_xor(sA, 4);   sB += __shfl_xor(sB, 4);
            sA += __shfl_xor(sA, 2);   sB += __shfl_xor(sB, 2);
            sA += __shfl_xor(sA, 1);   sB += __shfl_xor(sB, 1);
            if (q == 2 * i)     smem[wid][4 * i + half]     = sA + bias;
            if (q == 2 * i + 1) smem[wid][4 * i + 2 + half] = sB + bias;
        }
        // --- transpose: lane <- row base+lane (intra-wave LDS, no barrier) ---
        const int row = base + lane;
        const float val = smem[wid][lane];
        if (row < N) __builtin_nontemporal_store(val, loc + row);

        // --- segmented max over sorted bags within the 64-row window ---
        const int mybag = (row < N) ? __builtin_nontemporal_load(bag + row) : -1;
        float v = val;
        #pragma unroll
        for (int s = 1; s < 64; s <<= 1) {
            const float ov = __shfl_up(v, s);
            const int   ob = __shfl_up(mybag, s);
            if (lane >= s && ob == mybag) v = fmaxf(v, ov);
        }
        const int nxt = __shfl_down(mybag, 1);
        const bool tail = (lane == 63) || (nxt != mybag);
        if (tail && mybag >= 0)
            atomicMax(&Mu[mybag], flip_f32(v));               // ~1-2 per tile
    }
}

__global__ void linseg_finalize_kernel(const unsigned int* __restrict__ Mu,
                                       float* __restrict__ M, int B)
{
    const int i = blockIdx.x * blockDim.x + threadIdx.x;
    if (i < B) {
        const unsigned int u = Mu[i];
        M[i] = (u == 0u) ? 0.0f : unflip_f32(u);
    }
}

extern "C" void kernel_launch(void* const* d_in, const int* in_sizes, int n_in,
                              void* d_out, int out_size, void* d_ws, size_t ws_size,
                              hipStream_t stream) {
    const float* z    = (const float*)d_in[0];
    const int*   bag  = (const int*)  d_in[1];
    const float* W    = (const float*)d_in[2];
    const float* bptr = (const float*)d_in[3];

    const int N = in_sizes[1];            // bag_idx element count
    const int B = out_size - N;           // M is the first output chunk

    float* M_out   = (float*)d_out;       // [B]
    float* loc_out = (float*)d_out + B;   // [N]
    unsigned int* Mu = (unsigned int*)d_ws;

    // zero the per-bag key accumulator (graph-capturable async memset)
    (void)hipMemsetAsync(Mu, 0, (size_t)B * sizeof(unsigned int), stream);

    const int ntiles = (N + 63) >> 6;
    int blocks = (ntiles + 3) / 4;        // 4 waves per 256-thread block
    if (blocks > 2048) blocks = 2048;     // grid-stride the rest
    if (blocks < 1) blocks = 1;

    linseg_main_kernel<<<blocks, 256, 0, stream>>>(z, bag, W, bptr,
                                                   loc_out, Mu, N);
    linseg_finalize_kernel<<<(B + 255) / 256, 256, 0, stream>>>(Mu, M_out, B);
}